// Round 11
// baseline (1082.698 us; speedup 1.0000x reference)
//
#include <hip/hip_runtime.h>

// Gated delta-rule recurrence (Qwen3.5 GatedDeltaNet), B=4 S=2048 H=16 Dk=Dv=128, f32.
//
// R10 (from R9 measured: scan 590us, VALUBusy 59%, Occ 22%, VGPR 52):
//  R9 showed TLP works (VALU 36->59%) but 2 waves/SIMD leaves wall at 692cyc/step
//  with only ~408cyc issue. This round: 4 waves/SIMD + cheaper per-step code.
//  * Wave = 32 dk-lanes x 2 dv-cols (state 4 f32/lane). 4096 waves = 1024 blocks,
//    __launch_bounds__(256,4): 4 blocks/CU (LDS 33KB/block -> 135KB/CU fits).
//  * STRIDED dk ownership: lane dkl owns dk = dkl+32r (r=0..3). LDS k/q reads are
//    b32 at word dkl+32r: 32 lanes -> 32 distinct banks, conflict-free (a 16B/lane
//    layout would be 4-way conflicted at 32 lanes); upper 32 lanes broadcast.
//    DMA stays fully LINEAR (no global-source swizzle at all).
//  * reduce32 = verified reduce16 butterfly + ds_swizzle xor16 hop (0x401F).
//  * vp DMA exec-guarded to lanes<8 -> slot 1056B (vs 1280).
// Schedule identical to verified R4/R5: per-wave 8-slot LDS ring, 4-row DMA batches
// (8 vmcnt events), ONE s_waitcnt vmcnt(8) per 4-step group (2 batches in flight,
// never drained), lgkmcnt(0) then refill at group end. Math identical (absmax 9.8e-4).
//
// LDS slot (1056 B): [0,512) k row linear (word w at byte 4w), [512,1024) q row,
// [1024,1032) v[dv0],v[dv1], [1032,1040) pad, [1040,1056) pack4.
// kq dma16: lanes 0-31 k words 4l..4l+3, lanes 32-63 q. vp dma4 (lanes<8):
// lanes 0-1 v, 2-3 dup, 4-7 pack.
// pack (d_ws, 2MB) = (dec=exp(g), invk, invq*scale, beta*invk) per (b,h,s).

#define Bsz 4
#define Ssz 2048
#define Hsz 16
#define Dsz 128

constexpr int ROWS = Bsz * Ssz * Hsz;  // 131072
constexpr int VSTR = Hsz * Dsz;        // 2048 floats per step
constexpr float EPS = 1e-6f;
constexpr float SCALE = 0.08838834764831845f;  // 1/sqrt(128)

typedef float v2f __attribute__((ext_vector_type(2)));

template <int CTRL>
__device__ __forceinline__ float dpp_add(float x) {
  int y = __builtin_amdgcn_update_dpp(0, __float_as_int(x), CTRL, 0xF, 0xF, true);
  return x + __int_as_float(y);
}
// 0xB1=xor1, 0x4E=xor2, 0x141=ROW_HALF_MIRROR (==xor4 once quads uniform),
// 0x140=ROW_MIRROR (==xor8 once 8-groups uniform). 16-lane total in all 16 lanes.
__device__ __forceinline__ float reduce16(float x) {
  x = dpp_add<0xB1>(x);
  x = dpp_add<0x4E>(x);
  x = dpp_add<0x141>(x);
  x = dpp_add<0x140>(x);
  return x;
}
// + xor16 within each 32-lane group via ds_swizzle BitMode (16<<10)|0x1F.
__device__ __forceinline__ float reduce32(float x) {
  x = reduce16(x);
  int y = __builtin_amdgcn_ds_swizzle(__float_as_int(x), 0x401F);
  return x + __int_as_float(y);
}

// ---------------- prep: per (b,s,h) row scalars, 4 rows/wave ----------------
__global__ __launch_bounds__(256) void prep_kernel(
    const float* __restrict__ q, const float* __restrict__ k,
    const float* __restrict__ g, const float* __restrict__ beta,
    float4* __restrict__ pack) {
  int wid = threadIdx.x >> 6;
  int lane = threadIdx.x & 63;
  int lg = lane & 15;
  int rg = lane >> 4;
  int r = blockIdx.x * 16 + wid * 4 + rg;
  const float4* qp = reinterpret_cast<const float4*>(q + (size_t)r * Dsz);
  const float4* kp = reinterpret_cast<const float4*>(k + (size_t)r * Dsz);
  float4 qa = qp[lg * 2], qb = qp[lg * 2 + 1];
  float4 ka = kp[lg * 2], kb = kp[lg * 2 + 1];
  float sq = qa.x * qa.x + qa.y * qa.y + qa.z * qa.z + qa.w * qa.w +
             qb.x * qb.x + qb.y * qb.y + qb.z * qb.z + qb.w * qb.w;
  float sk = ka.x * ka.x + ka.y * ka.y + ka.z * ka.z + ka.w * ka.w +
             kb.x * kb.x + kb.y * kb.y + kb.z * kb.z + kb.w * kb.w;
  sq = reduce16(sq);
  sk = reduce16(sk);
  if (lg == 0) {
    float xq = sq + EPS;
    float rq = rsqrtf(xq);
    rq = rq * (1.5f - 0.5f * xq * rq * rq);  // Newton refine
    float xk = sk + EPS;
    float rk = rsqrtf(xk);
    rk = rk * (1.5f - 0.5f * xk * rk * rk);
    float dec = expf(g[r]);
    float bi = beta[r] * rk;
    int h = r % Hsz;
    int s = (r / Hsz) % Ssz;
    int b = r / (Hsz * Ssz);
    pack[(size_t)(b * Hsz + h) * Ssz + s] = make_float4(dec, rk, rq * SCALE, bi);
  }
}

// ---------------- scan ----------------
#define DDEPTH 8                  // ring slots
#define BATCH 4                   // rows per DMA batch (8 vmcnt events)
#define SLOT_B 1056               // 512 k + 512 q + 8 v + 8 pad + 16 pack
#define WAVE_B (DDEPTH * SLOT_B)  // 8448 bytes per wave

__device__ __forceinline__ void dma16(unsigned long long g, unsigned int l) {
  __builtin_amdgcn_global_load_lds(
      (const __attribute__((address_space(1))) void*)g,
      (__attribute__((address_space(3))) void*)(unsigned long long)l, 16, 0, 0);
}
__device__ __forceinline__ void dma4(unsigned long long g, unsigned int l) {
  __builtin_amdgcn_global_load_lds(
      (const __attribute__((address_space(1))) void*)g,
      (__attribute__((address_space(3))) void*)(unsigned long long)l, 4, 0, 0);
}

struct Buf2 {
  v2f kr0, kr1, qr0, qr1;
  float4 p;
  float vv;
};

// Strided reads: lane dkl reads words {dkl, dkl+32} and {dkl+64, dkl+96} of the
// 128-word k row (then q at +128 words). 32 lanes -> 32 distinct banks per word,
// conflict-free; lanes 32-63 read the same addresses (broadcast, free).
__device__ __forceinline__ void ld_buf2(Buf2& b, const char* slot, int dkl, int dvg) {
  const float* sf = (const float*)slot;
  b.kr0 = (v2f){sf[dkl], sf[dkl + 32]};
  b.kr1 = (v2f){sf[dkl + 64], sf[dkl + 96]};
  b.qr0 = (v2f){sf[128 + dkl], sf[128 + dkl + 32]};
  b.qr1 = (v2f){sf[128 + dkl + 64], sf[128 + dkl + 96]};
  b.vv = sf[256 + dvg];
  b.p = *(const float4*)(slot + 1040);
}

// One recurrence step for this lane's 4 state elems (2 packed pairs).
__device__ __forceinline__ float step_compute2(const Buf2& b, v2f (&st)[2]) {
  v2f a = st[0] * b.kr0;
  a = __builtin_elementwise_fma(st[1], b.kr1, a);
  float acc = a.x + a.y;
  acc = reduce32(acc);  // sum st*k_raw over all 128 dk
  float dec = b.p.x;
  float kv = acc * dec * b.p.y;    // * exp(g) * invk
  float dl = (b.vv - kv) * b.p.w;  // * beta*invk
  v2f dec2 = (v2f){dec, dec};
  v2f dl2 = (v2f){dl, dl};
  st[0] = __builtin_elementwise_fma(st[0], dec2, b.kr0 * dl2);
  st[1] = __builtin_elementwise_fma(st[1], dec2, b.kr1 * dl2);
  v2f o = st[0] * b.qr0;
  o = __builtin_elementwise_fma(st[1], b.qr1, o);
  float oacc = o.x + o.y;
  oacc = reduce32(oacc);
  return oacc * b.p.z;  // * invq * 1/sqrt(128)
}

__global__ __launch_bounds__(256, 4) void scan_kernel(
    const float* __restrict__ q, const float* __restrict__ k,
    const float* __restrict__ v, const float4* __restrict__ pack,
    float* __restrict__ out, float* __restrict__ stateOut) {
  __shared__ __align__(16) char smem[4 * WAVE_B];  // 33792 B

  const int blk = blockIdx.x;
  const int bh = blk & 63;  // 16 blocks of one bh -> same XCD (blk%8 == bh%8)
  const int cc = blk >> 6;  // dv chunk 0..15 (8 dv each)
  const int tid = threadIdx.x;
  const int lane = tid & 63;
  const int wid = __builtin_amdgcn_readfirstlane(tid >> 6);
  const int dkl = lane & 31;  // dk-lane: owns dk = dkl + 32r, r=0..3
  const int dvg = lane >> 5;  // dv within wave's 2
  const int dv0 = cc * 8 + wid * 2;
  const int dv = dv0 + dvg;

  const size_t base = ((size_t)(bh >> 4) * Ssz * Hsz + (bh & 15)) * Dsz;
  const float4* pp = pack + (size_t)bh * Ssz;

  const unsigned int wb3 =
      (unsigned int)(unsigned long long)(void*)smem + (unsigned int)(wid * WAVE_B);
  const char* wbg = smem + wid * WAVE_B;

  // kq DMA source (row 0), LINEAR: lane li<32 -> k words 4li..4li+3; li>=32 -> q.
  const int li = lane & 31;
  unsigned long long kq_g =
      (unsigned long long)(uintptr_t)(((lane < 32) ? k : q) + base + 4 * li);
  // vp DMA source: lanes 0-1 v[dv0+lane], lanes 2-3 dup pack, lanes 4-7 pack[0..3].
  unsigned long long vp_g;
  unsigned int vp_stride;
  if (lane < 2) {
    vp_g = (unsigned long long)(uintptr_t)(v + base + dv0 + lane);
    vp_stride = VSTR * 4;  // 8192 B per row
  } else {
    int pc = (lane >= 4 && lane < 8) ? (lane - 4) : 0;
    vp_g = (unsigned long long)(uintptr_t)((const float*)pp + pc);
    vp_stride = 16;
  }

  // Prologue: rows 0..7 into slots 0..7 (16 vmcnt events); pointers end at row 8.
#pragma unroll
  for (int r = 0; r < DDEPTH; ++r) {
    dma16(kq_g, wb3 + r * SLOT_B);
    if (lane < 8) dma4(vp_g, wb3 + r * SLOT_B + 1024);
    kq_g += VSTR * 4;
    vp_g += vp_stride;
  }
  int nrow = DDEPTH;  // saturates at 2047

  v2f st[2];
  st[0] = (v2f){0.f, 0.f};
  st[1] = (v2f){0.f, 0.f};

  float* outp = out + base + (size_t)dkl * VSTR + dv;  // lane dkl archives row sb+dkl
  float ocap = 0.f;
  Buf2 A, Bb;

  for (int sb = 0; sb < Ssz; sb += 32) {
#pragma unroll
    for (int gg = 0; gg < 8; ++gg) {
      const int s0 = (gg & 1) * BATCH;  // slot base 0 or 4 (compile-time)
      // The 4 rows about to be consumed have landed; newest batch stays in flight.
      asm volatile("s_waitcnt vmcnt(8)" ::: "memory");
      ld_buf2(A, wbg + (s0 + 0) * SLOT_B, dkl, dvg);
      __builtin_amdgcn_sched_barrier(0);
      ld_buf2(Bb, wbg + (s0 + 1) * SLOT_B, dkl, dvg);
      __builtin_amdgcn_sched_barrier(0);
      {
        float o = step_compute2(A, st);
        ocap = (dkl == gg * 4 + 0) ? o : ocap;
      }
      ld_buf2(A, wbg + (s0 + 2) * SLOT_B, dkl, dvg);
      __builtin_amdgcn_sched_barrier(0);
      {
        float o = step_compute2(Bb, st);
        ocap = (dkl == gg * 4 + 1) ? o : ocap;
      }
      ld_buf2(Bb, wbg + (s0 + 3) * SLOT_B, dkl, dvg);
      __builtin_amdgcn_sched_barrier(0);
      {
        float o = step_compute2(A, st);
        ocap = (dkl == gg * 4 + 2) ? o : ocap;
      }
      {
        float o = step_compute2(Bb, st);
        ocap = (dkl == gg * 4 + 3) ? o : ocap;
      }
      if (gg == 7) {
        *outp = ocap;  // 64 lanes = 32 rows x 2 dv, once per 32 steps
        outp += 32 * VSTR;
      }
      // Slot regs fully consumed; refill slots s0..s0+3 with rows nrow..+3.
      asm volatile("s_waitcnt lgkmcnt(0)" ::: "memory");
#pragma unroll
      for (int j = 0; j < BATCH; ++j) {
        dma16(kq_g, wb3 + (s0 + j) * SLOT_B);
        if (lane < 8) dma4(vp_g, wb3 + (s0 + j) * SLOT_B + 1024);
        if (nrow < Ssz - 1) {  // saturate at row 2047 (stays in bounds)
          kq_g += VSTR * 4;
          vp_g += vp_stride;
          ++nrow;
        }
      }
    }
  }

  // final state: stateOut[(b*H+h)*Dk*Dv + dk*Dv + dv], lane owns dk = dkl+32r.
  float* sp = stateOut + ((size_t)bh * Dsz + dkl) * Dsz + dv;
  sp[0 * 32 * Dsz] = st[0].x;
  sp[1 * 32 * Dsz] = st[0].y;
  sp[2 * 32 * Dsz] = st[1].x;
  sp[3 * 32 * Dsz] = st[1].y;
}

extern "C" void kernel_launch(void* const* d_in, const int* in_sizes, int n_in,
                              void* d_out, int out_size, void* d_ws, size_t ws_size,
                              hipStream_t stream) {
  const float* q = (const float*)d_in[0];
  const float* k = (const float*)d_in[1];
  const float* v = (const float*)d_in[2];
  const float* g = (const float*)d_in[3];
  const float* beta = (const float*)d_in[4];
  float* out = (float*)d_out;
  float* stateOut = out + (size_t)Bsz * Ssz * Hsz * Dsz;
  float4* pack = (float4*)d_ws;  // 64*2048*16B = 2 MB

  prep_kernel<<<ROWS / 16, 256, 0, stream>>>(q, k, g, beta, pack);
  scan_kernel<<<1024, 256, 0, stream>>>(q, k, v, pack, out, stateOut);
}